// Round 1
// baseline (1715.637 us; speedup 1.0000x reference)
//
#include <hip/hip_runtime.h>
#include <hip/hip_bf16.h>

// Problem constants
#define BATCH   64
#define CHAN    384
#define HW      1024
#define SM_PB   (HW * HW)          // score elements per batch = 1048576
#define OUT_OFF 576                // action floats before score matrix
#define KTOP    1024
#define NBUCKET 4096
#define CAND_CAP 8192

// Workspace byte offsets
#define WS_INV_CUR   0                      // 64*1024*4 = 262144
#define WS_INV_GOAL  262144                 // 262144
#define WS_HIST      524288                 // 64*4096*4 = 1048576
#define WS_CNT       1572864                // 64*4 (padded to 256)
#define WS_TBUF      1573120                // 64*4 (padded to 256)
#define WS_CAND      1573376                // 64*8192*8 = 4194304
#define WS_FEATS     5767680                // 64*3072*4 = 786432
#define WS_H1        6554112                // 64*1024*4 = 262144
#define WS_H2        6816256                // 64*256*4  = 65536
// total ~6.9 MB

__device__ __forceinline__ unsigned mono_key(float f) {
    unsigned u = __float_as_uint(f);
    return u ^ ((u & 0x80000000u) ? 0xFFFFFFFFu : 0x80000000u);
}

// ---------------- 1. per-location inverse L2 norms over channels ----------
__global__ void norm_kernel(const float* __restrict__ cur,
                            const float* __restrict__ goal,
                            float* __restrict__ inv_cur,
                            float* __restrict__ inv_goal) {
    const int p = blockIdx.x * 256 + threadIdx.x;   // 0..1023
    const int b = blockIdx.y;
    const float* pc = cur  + (size_t)b * CHAN * HW + p;
    const float* pg = goal + (size_t)b * CHAN * HW + p;
    float sc = 0.f, sg = 0.f;
    for (int c = 0; c < CHAN; ++c) {
        float vc = pc[c * HW];
        float vg = pg[c * HW];
        sc += vc * vc;
        sg += vg * vg;
    }
    inv_cur[b * HW + p]  = 1.0f / fmaxf(sqrtf(sc), 1e-12f);
    inv_goal[b * HW + p] = 1.0f / fmaxf(sqrtf(sg), 1e-12f);
}

// ---------------- 2. batched score GEMM (f32 vector ALU) ------------------
// S[b][m][n] = inv_cur[b][m]*inv_goal[b][n]*sum_c cur[b][c][m]*goal[b][c][n]
__global__ __launch_bounds__(256)
void gemm_kernel(const float* __restrict__ cur,
                 const float* __restrict__ goal,
                 const float* __restrict__ inv_cur,
                 const float* __restrict__ inv_goal,
                 float* __restrict__ score) {
    const int b  = blockIdx.z;
    const int m0 = blockIdx.x * 64;
    const int n0 = blockIdx.y * 64;
    __shared__ float As[16][64];
    __shared__ float Bs[16][64];
    const int tid = threadIdx.x;
    const int tn = tid & 15;        // 0..15 -> n groups of 4
    const int tm = tid >> 4;        // 0..15 -> m groups of 4
    const int ldk = tid >> 4;       // row (k) to load
    const int ldc = (tid & 15) * 4; // 4-float column within the 64-wide tile
    const float* A = cur  + (size_t)b * CHAN * HW;
    const float* B = goal + (size_t)b * CHAN * HW;
    float acc[4][4] = {};

    for (int k0 = 0; k0 < CHAN; k0 += 16) {
        __syncthreads();
        *(float4*)&As[ldk][ldc] = *(const float4*)(A + (k0 + ldk) * HW + m0 + ldc);
        *(float4*)&Bs[ldk][ldc] = *(const float4*)(B + (k0 + ldk) * HW + n0 + ldc);
        __syncthreads();
#pragma unroll
        for (int kk = 0; kk < 16; ++kk) {
            float4 a4 = *(float4*)&As[kk][tm * 4];
            float4 b4 = *(float4*)&Bs[kk][tn * 4];
            float a[4] = {a4.x, a4.y, a4.z, a4.w};
            float bb[4] = {b4.x, b4.y, b4.z, b4.w};
#pragma unroll
            for (int i = 0; i < 4; ++i)
#pragma unroll
                for (int j = 0; j < 4; ++j)
                    acc[i][j] += a[i] * bb[j];
        }
    }

    float im[4], inj[4];
#pragma unroll
    for (int i = 0; i < 4; ++i) im[i]  = inv_cur[b * HW + m0 + tm * 4 + i];
#pragma unroll
    for (int j = 0; j < 4; ++j) inj[j] = inv_goal[b * HW + n0 + tn * 4 + j];

    float* out = score + (size_t)b * SM_PB;
#pragma unroll
    for (int i = 0; i < 4; ++i) {
        int m = m0 + tm * 4 + i;
        float4 v;
        v.x = acc[i][0] * im[i] * inj[0];
        v.y = acc[i][1] * im[i] * inj[1];
        v.z = acc[i][2] * im[i] * inj[2];
        v.w = acc[i][3] * im[i] * inj[3];
        *(float4*)(out + (size_t)m * HW + n0 + tn * 4) = v;
    }
}

// ---------------- 3. per-batch histogram of key top-12 bits ---------------
__global__ void hist_kernel(const float* __restrict__ score,
                            unsigned* __restrict__ ghist) {
    const int slice = blockIdx.x;   // 0..15
    const int b     = blockIdx.y;
    const int tid   = threadIdx.x;
    __shared__ unsigned hs[NBUCKET];
    for (int i = tid; i < NBUCKET; i += 256) hs[i] = 0;
    __syncthreads();
    const float4* base = (const float4*)(score + (size_t)b * SM_PB + slice * 65536);
    for (int it = 0; it < 64; ++it) {
        float4 v = base[it * 256 + tid];
        atomicAdd(&hs[mono_key(v.x) >> 20], 1u);
        atomicAdd(&hs[mono_key(v.y) >> 20], 1u);
        atomicAdd(&hs[mono_key(v.z) >> 20], 1u);
        atomicAdd(&hs[mono_key(v.w) >> 20], 1u);
    }
    __syncthreads();
    for (int i = tid; i < NBUCKET; i += 256)
        if (hs[i]) atomicAdd(&ghist[b * NBUCKET + i], hs[i]);
}

// ---------------- 4. find threshold bucket per batch ----------------------
__global__ void thresh_kernel(const unsigned* __restrict__ ghist,
                              unsigned* __restrict__ tbuf) {
    const int b = blockIdx.x;
    const int tid = threadIdx.x;
    __shared__ unsigned partial[256];
    unsigned s = 0;
    for (int j = 0; j < 16; ++j) s += ghist[b * NBUCKET + tid * 16 + j];
    partial[tid] = s;
    __syncthreads();
    if (tid == 0) {
        unsigned cum = 0;
        int T = 0;
        for (int t = 255; t >= 0; --t) {
            if (cum + partial[t] >= KTOP) {
                for (int k = t * 16 + 15; k >= t * 16; --k) {
                    cum += ghist[b * NBUCKET + k];
                    if (cum >= KTOP) { T = k; break; }
                }
                break;
            }
            cum += partial[t];
        }
        tbuf[b] = (unsigned)T;
    }
}

// ---------------- 5. collect candidates (bucket >= T) ---------------------
__global__ void collect_kernel(const float* __restrict__ score,
                               const unsigned* __restrict__ tbuf,
                               unsigned* __restrict__ cnt,
                               unsigned long long* __restrict__ cand) {
    const int slice = blockIdx.x;
    const int b     = blockIdx.y;
    const int tid   = threadIdx.x;
    const unsigned T = tbuf[b];
    const float4* base = (const float4*)(score + (size_t)b * SM_PB + slice * 65536);
    for (int it = 0; it < 64; ++it) {
        int e0 = slice * 65536 + (it * 256 + tid) * 4;
        float4 v = base[it * 256 + tid];
        float vals[4] = {v.x, v.y, v.z, v.w};
#pragma unroll
        for (int c = 0; c < 4; ++c) {
            unsigned key = mono_key(vals[c]);
            if ((key >> 20) >= T) {
                unsigned pos = atomicAdd(&cnt[b], 1u);
                if (pos < CAND_CAP)
                    cand[(size_t)b * CAND_CAP + pos] =
                        ((unsigned long long)key << 32) |
                        (unsigned long long)(0xFFFFFFFFu - (unsigned)(e0 + c));
            }
        }
    }
}

// ---------------- 6. select top-K, sort by index, build feats -------------
__global__ __launch_bounds__(1024)
void select_kernel(const unsigned long long* __restrict__ cand,
                   const unsigned* __restrict__ cnt,
                   const float* __restrict__ score,
                   float* __restrict__ feats) {
    const int b = blockIdx.x;
    const int tid = threadIdx.x;
    __shared__ unsigned long long arr[CAND_CAP];
    __shared__ unsigned idxs[KTOP];
    unsigned n = cnt[b];
    if (n > CAND_CAP) n = CAND_CAP;
    for (int i = tid; i < CAND_CAP; i += 1024)
        arr[i] = (i < (int)n) ? cand[(size_t)b * CAND_CAP + i] : 0ULL;
    __syncthreads();

    // bitonic sort descending on composite (key desc, idx asc)
    for (unsigned size = 2; size <= CAND_CAP; size <<= 1) {
        for (unsigned stride = size >> 1; stride > 0; stride >>= 1) {
            for (int i = tid; i < CAND_CAP; i += 1024) {
                int j = i ^ stride;
                if (j > i) {
                    unsigned long long a = arr[i], c = arr[j];
                    bool desc = ((i & size) == 0);
                    if (desc ? (a < c) : (a > c)) { arr[i] = c; arr[j] = a; }
                }
            }
            __syncthreads();
        }
    }

    // first K entries are the top-K; recover indices
    unsigned myidx = 0xFFFFFFFFu - (unsigned)(arr[tid] & 0xFFFFFFFFu);
    __syncthreads();
    idxs[tid] = myidx;
    __syncthreads();

    // bitonic sort ascending on index
    for (unsigned size = 2; size <= KTOP; size <<= 1) {
        for (unsigned stride = size >> 1; stride > 0; stride >>= 1) {
            int i = tid;
            int j = i ^ stride;
            if (j > i && i < KTOP) {
                unsigned a = idxs[i], c = idxs[j];
                bool asc = ((i & size) == 0);
                if (asc ? (a > c) : (a < c)) { idxs[i] = c; idxs[j] = a; }
            }
            __syncthreads();
        }
    }

    unsigned idx = idxs[tid];
    float val = score[(size_t)b * SM_PB + idx];
    float* f = feats + (size_t)b * (KTOP * 3) + tid * 3;
    f[0] = (float)(idx >> 10);
    f[1] = (float)(idx & 1023);
    f[2] = val;
}

__device__ __forceinline__ float silu(float x) {
    return x / (1.0f + expf(-x));
}

// ---------------- 7. MLP layer 1: 3072 -> 1024 ----------------------------
__global__ void mlp1_kernel(const float* __restrict__ feats,
                            const float* __restrict__ W1,
                            const float* __restrict__ b1,
                            float* __restrict__ h1) {
    __shared__ float fs[3072];
    const int b = blockIdx.y, chunk = blockIdx.x, tid = threadIdx.x;
    for (int i = tid; i < 3072; i += 256) fs[i] = feats[(size_t)b * 3072 + i];
    __syncthreads();
    const int o = chunk * 256 + tid;
    float acc = b1[o];
    for (int k = 0; k < 3072; ++k) acc += fs[k] * W1[(size_t)k * 1024 + o];
    h1[(size_t)b * 1024 + o] = silu(acc);
}

// ---------------- 8. MLP layer 2: 1024 -> 256 -----------------------------
__global__ void mlp2_kernel(const float* __restrict__ h1,
                            const float* __restrict__ W2,
                            const float* __restrict__ b2,
                            float* __restrict__ h2) {
    __shared__ float hs[1024];
    const int b = blockIdx.x, tid = threadIdx.x;
    for (int i = tid; i < 1024; i += 256) hs[i] = h1[(size_t)b * 1024 + i];
    __syncthreads();
    float acc = b2[tid];
    for (int k = 0; k < 1024; ++k) acc += hs[k] * W2[(size_t)k * 256 + tid];
    h2[(size_t)b * 256 + tid] = silu(acc);
}

// ---------------- 9. MLP tail: 256->64->16->heads -------------------------
__global__ void tail_kernel(const float* __restrict__ h2,
                            const float* __restrict__ W3, const float* __restrict__ b3,
                            const float* __restrict__ W4, const float* __restrict__ b4,
                            const float* __restrict__ Wx, const float* __restrict__ bx,
                            const float* __restrict__ Wy, const float* __restrict__ by,
                            const float* __restrict__ Wr, const float* __restrict__ br,
                            float* __restrict__ action) {
    const int b = blockIdx.x, t = threadIdx.x;  // 64 threads
    __shared__ float h2s[256];
    __shared__ float h3s[64];
    __shared__ float h4s[16];
    for (int i = t; i < 256; i += 64) h2s[i] = h2[(size_t)b * 256 + i];
    __syncthreads();
    {
        float acc = b3[t];
        for (int k = 0; k < 256; ++k) acc += h2s[k] * W3[k * 64 + t];
        h3s[t] = silu(acc);
    }
    __syncthreads();
    if (t < 16) {
        float acc = b4[t];
        for (int k = 0; k < 64; ++k) acc += h3s[k] * W4[k * 16 + t];
        h4s[t] = silu(acc);
    }
    __syncthreads();
    if (t < 9) {
        int head = t / 3, j = t % 3;
        const float* Wh = (head == 0) ? Wx : (head == 1) ? Wy : Wr;
        const float* bh = (head == 0) ? bx : (head == 1) ? by : br;
        float acc = bh[j];
        for (int k = 0; k < 16; ++k) acc += h4s[k] * Wh[k * 3 + j];
        action[b * 9 + t] = acc;
    }
}

extern "C" void kernel_launch(void* const* d_in, const int* in_sizes, int n_in,
                              void* d_out, int out_size, void* d_ws, size_t ws_size,
                              hipStream_t stream) {
    const float* cur  = (const float*)d_in[0];
    const float* goal = (const float*)d_in[1];
    const float* W1 = (const float*)d_in[2];
    const float* b1 = (const float*)d_in[3];
    const float* W2 = (const float*)d_in[4];
    const float* b2 = (const float*)d_in[5];
    const float* W3 = (const float*)d_in[6];
    const float* b3 = (const float*)d_in[7];
    const float* W4 = (const float*)d_in[8];
    const float* b4 = (const float*)d_in[9];
    const float* Wx = (const float*)d_in[10];
    const float* bx = (const float*)d_in[11];
    const float* Wy = (const float*)d_in[12];
    const float* by = (const float*)d_in[13];
    const float* Wr = (const float*)d_in[14];
    const float* br = (const float*)d_in[15];

    float* out = (float*)d_out;
    float* score = out + OUT_OFF;
    char* ws = (char*)d_ws;

    float* inv_cur  = (float*)(ws + WS_INV_CUR);
    float* inv_goal = (float*)(ws + WS_INV_GOAL);
    unsigned* ghist = (unsigned*)(ws + WS_HIST);
    unsigned* cnt   = (unsigned*)(ws + WS_CNT);
    unsigned* tbuf  = (unsigned*)(ws + WS_TBUF);
    unsigned long long* cand = (unsigned long long*)(ws + WS_CAND);
    float* feats = (float*)(ws + WS_FEATS);
    float* h1    = (float*)(ws + WS_H1);
    float* h2    = (float*)(ws + WS_H2);

    // zero histogram + counters (ws is poisoned 0xAA before each call)
    hipMemsetAsync(ws + WS_HIST, 0, (size_t)BATCH * NBUCKET * 4 + 256, stream);

    norm_kernel<<<dim3(4, BATCH), 256, 0, stream>>>(cur, goal, inv_cur, inv_goal);
    gemm_kernel<<<dim3(16, 16, BATCH), 256, 0, stream>>>(cur, goal, inv_cur, inv_goal, score);
    hist_kernel<<<dim3(16, BATCH), 256, 0, stream>>>(score, ghist);
    thresh_kernel<<<dim3(BATCH), 256, 0, stream>>>(ghist, tbuf);
    collect_kernel<<<dim3(16, BATCH), 256, 0, stream>>>(score, tbuf, cnt, cand);
    select_kernel<<<dim3(BATCH), 1024, 0, stream>>>(cand, cnt, score, feats);
    mlp1_kernel<<<dim3(4, BATCH), 256, 0, stream>>>(feats, W1, b1, h1);
    mlp2_kernel<<<dim3(BATCH), 256, 0, stream>>>(h1, W2, b2, h2);
    tail_kernel<<<dim3(BATCH), 64, 0, stream>>>(h2, W3, b3, W4, b4,
                                                Wx, bx, Wy, by, Wr, br, out);
}